// Round 5
// baseline (106.882 us; speedup 1.0000x reference)
//
#include <hip/hip_runtime.h>
#include <hip/hip_bf16.h>
#include <hip/hip_fp16.h>

typedef _Float16 f16;
typedef __attribute__((ext_vector_type(8))) _Float16 f16x8;
typedef __attribute__((ext_vector_type(4))) float f32x4;

#define DIM     2048
#define BROWS   8192
#define NCOLS   1221      // 111 nodes * 11
#define NPAD    1280      // 10 tiles of 128
#define NNODES  111
#define BM      128
#define BN      128
#define BK      32
#define NKT     (DIM / BK)    // 64 K-steps
#define MT      (BROWS / BM)  // 64
#define NT      (NPAD / BN)   // 10
// Fragment image per (tile, kt32): 512 chunks x 16B = 8 KB = 4096 f16.
// chunk c = g*64 + l ; lane l (r=l&15,q=l>>4) holds row g*16+r, k = q*8..+8.
// (Byte-identical to round-3 BK=64 images split in half -> prep kernels unchanged.)

// ---------------------------------------------------------------------------
// prep_x: x f32 [8192][2048] -> Xf f16 fragment-ordered (64 mt x 64 kt32 images)
// ---------------------------------------------------------------------------
__global__ __launch_bounds__(256) void prep_x(const float* __restrict__ X,
                                              f16* __restrict__ Xf) {
    __shared__ float T[128 * 68];
    int blk = blockIdx.x;                      // mt*32 + kt64
    int mt = blk >> 5, kt = blk & 31;
    int t = threadIdx.x;
    int row = t >> 1, half = t & 1;
    const float* src = X + (size_t)(mt * 128 + row) * DIM + kt * 64 + half * 32;
    float* dst = T + row * 68 + half * 32;
    #pragma unroll
    for (int i = 0; i < 8; ++i) ((f32x4*)dst)[i] = ((const f32x4*)src)[i];
    __syncthreads();
    int w = t >> 6, l = t & 63, r = l & 15, q = l >> 4;
    f16* out = Xf + (size_t)blk * 8192;
    #pragma unroll
    for (int p = 0; p < 4; ++p) {
        int gk = p * 4 + w;                    // = kk*8 + g
        int kk = gk >> 3, g = gk & 7;
        const float* s = T + (g * 16 + r) * 68 + kk * 32 + q * 8;
        f32x4 a = *(const f32x4*)s;
        f32x4 b = *(const f32x4*)(s + 4);
        f16x8 h;
        h[0] = (f16)a[0]; h[1] = (f16)a[1]; h[2] = (f16)a[2]; h[3] = (f16)a[3];
        h[4] = (f16)b[0]; h[5] = (f16)b[1]; h[6] = (f16)b[2]; h[7] = (f16)b[3];
        *(f16x8*)(out + (size_t)(p * 256 + t) * 8) = h;   // coalesced
    }
}

// ---------------------------------------------------------------------------
// prep_b: W f32 [111][2048][11] -> Bf f16 fragment-ordered
// ---------------------------------------------------------------------------
__global__ void prep_b(const float* __restrict__ W, f16* __restrict__ Bf) {
    int idx = blockIdx.x * 256 + threadIdx.x;  // 327,680
    int c = idx & 1023, img = idx >> 10;       // img = nt*32 + kt64
    int nt = img >> 5, kt = img & 31;
    int kk = c >> 9, g = (c >> 6) & 7, l = c & 63, r = l & 15, q = l >> 4;
    int col = nt * 128 + g * 16 + r;
    int d0  = kt * 64 + kk * 32 + q * 8;
    f16x8 v;
    if (col < NCOLS) {
        int n = col / 11, k = col - n * 11;
        const float* src = W + ((size_t)n * DIM + d0) * 11 + k;
        #pragma unroll
        for (int e = 0; e < 8; ++e) v[e] = (f16)src[(size_t)e * 11];
    } else {
        #pragma unroll
        for (int e = 0; e < 8; ++e) v[e] = (f16)0.f;
    }
    *(f16x8*)(Bf + (size_t)idx * 8) = v;
}

// ---------------------------------------------------------------------------
// GEMM: 128x128 tile, BK=32, 8 waves (wave-tile 64x32), DOUBLE-buffered LDS,
// raw s_barrier + counted s_waitcnt vmcnt(2): tile t+1's global_load_lds stay
// in flight across the barriers while tile t is computed (T3-min + T4).
// ---------------------------------------------------------------------------
__global__ __launch_bounds__(512) void gemm_f16(const f16* __restrict__ Xf,
                                                const f16* __restrict__ Bf,
                                                f16* __restrict__ Lh) {
    __shared__ __align__(16) f16 As[2][4096];  // 8 KB per buffer
    __shared__ __align__(16) f16 Bs[2][4096];

    int bid = blockIdx.x;                      // 640 = 8 XCDs * 80
    int swz = (bid & 7) * 80 + (bid >> 3);
    int mt = swz / 10, nt = swz - mt * 10;

    int t = threadIdx.x, w = t >> 6, l = t & 63, r = l & 15, q = l >> 4;
    int wm = w >> 2, wn = w & 3;               // 2 x 4 wave grid, wave tile 64x32

    const f16* abase = Xf + (size_t)mt * 262144 + (size_t)t * 8;   // mt panel
    const f16* bbase = Bf + (size_t)nt * 262144 + (size_t)t * 8;   // nt panel

    f32x4 acc[4][2];
    #pragma unroll
    for (int i = 0; i < 4; ++i)
        #pragma unroll
        for (int j = 0; j < 2; ++j) acc[i][j] = (f32x4)0.f;

#define STAGE(KT, C)                                                             \
    {                                                                            \
        __builtin_amdgcn_global_load_lds(                                        \
            (const __attribute__((address_space(1))) void*)(abase + (size_t)(KT) * 4096), \
            (__attribute__((address_space(3))) void*)(&As[C][w * 512]), 16, 0, 0);        \
        __builtin_amdgcn_global_load_lds(                                        \
            (const __attribute__((address_space(1))) void*)(bbase + (size_t)(KT) * 4096), \
            (__attribute__((address_space(3))) void*)(&Bs[C][w * 512]), 16, 0, 0);        \
    }

#define COMPUTE(C)                                                               \
    {                                                                            \
        f16x8 af[4], bfr[2];                                                     \
        _Pragma("unroll")                                                        \
        for (int m = 0; m < 4; ++m)                                              \
            af[m] = *(const f16x8*)(&As[C][((wm * 4 + m) * 64 + l) * 8]);        \
        _Pragma("unroll")                                                        \
        for (int n = 0; n < 2; ++n)                                              \
            bfr[n] = *(const f16x8*)(&Bs[C][((wn * 2 + n) * 64 + l) * 8]);       \
        _Pragma("unroll")                                                        \
        for (int m = 0; m < 4; ++m)                                              \
            _Pragma("unroll")                                                    \
            for (int n = 0; n < 2; ++n)                                          \
                acc[m][n] = __builtin_amdgcn_mfma_f32_16x16x32_f16(af[m], bfr[n], acc[m][n], 0, 0, 0); \
    }

    // prologue: stage tile 0 into buffer 0 (2 loads/thread in flight)
    STAGE(0, 0)

    #pragma unroll 2
    for (int kt = 0; kt < NKT - 1; ++kt) {
        int cc = kt & 1, cn = cc ^ 1;
        // issue tile kt+1 (2 more loads; oldest 2 = tile kt)
        STAGE(kt + 1, cn)
        // wait tile kt landed (tile kt+1's 2 loads stay in flight), then sync
        asm volatile("s_waitcnt vmcnt(2)" ::: "memory");
        __builtin_amdgcn_s_barrier();
        asm volatile("" ::: "memory");
        COMPUTE(cc)
        // all ds_reads delivered, then sync before next STAGE overwrites buf cc
        asm volatile("s_waitcnt lgkmcnt(0)" ::: "memory");
        __builtin_amdgcn_s_barrier();
        asm volatile("" ::: "memory");
    }
    // tail: tile 63 (buffer 1), nothing left to prefetch
    asm volatile("s_waitcnt vmcnt(0)" ::: "memory");
    __builtin_amdgcn_s_barrier();
    asm volatile("" ::: "memory");
    COMPUTE(1)

#undef STAGE
#undef COMPUTE

    // C write (f16): col = lane&15, row = (lane>>4)*4 + j (verified r1-r4)
    #pragma unroll
    for (int m = 0; m < 4; ++m) {
        int row = mt * 128 + wm * 64 + m * 16 + q * 4;
        #pragma unroll
        for (int n = 0; n < 2; ++n) {
            int col = nt * 128 + wn * 32 + n * 16 + r;
            #pragma unroll
            for (int j = 0; j < 4; ++j)
                Lh[(size_t)(row + j) * NPAD + col] = (f16)acc[m][n][j];
        }
    }
}

// ---------- epilogue: softmax per node (k=11) + 3-level product tree ----------
__global__ void tree_epi(const f16* __restrict__ L, const float* __restrict__ bias,
                         float* __restrict__ out) {
    __shared__ float P[4][NNODES * 11];
    __shared__ f16 R[4][NPAD];
    int w = threadIdx.x >> 6, l = threadIdx.x & 63;
    int row = blockIdx.x * 4 + w;

    // stage the row with vectorized loads (160 f16x8 chunks per row)
    const f16x8* src = (const f16x8*)(L + (size_t)row * NPAD);
    f16x8* dst = (f16x8*)R[w];
    dst[l]      = src[l];
    dst[l + 64] = src[l + 64];
    if (l < 32) dst[l + 128] = src[l + 128];
    // same-wave LDS write->read: hardware-ordered, compiler inserts lgkmcnt

    for (int n = l; n < NNODES; n += 64) {
        float v[11], mx = -1e30f;
        #pragma unroll
        for (int k = 0; k < 11; ++k) { v[k] = (float)R[w][n * 11 + k] + bias[n * 11 + k]; mx = fmaxf(mx, v[k]); }
        float s = 0.f;
        #pragma unroll
        for (int k = 0; k < 11; ++k) { v[k] = __expf(v[k] - mx); s += v[k]; }
        float inv = 1.f / s;
        #pragma unroll
        for (int k = 0; k < 11; ++k) P[w][n * 11 + k] = v[k] * inv;
    }
    __syncthreads();
    const float* Pw = P[w];
    for (int c = l; c < 1000; c += 64) {
        int i  = c / 100;
        int j  = (c % 100) / 10;
        int mm = c % 10;
        float p = Pw[1 + i] * Pw[(1 + i) * 11 + 1 + j] * Pw[(11 + 10 * i + j) * 11 + 1 + mm];
        out[(size_t)row * 1000 + c] = p;
    }
    if (row == 0 && threadIdx.x == 0) out[(size_t)BROWS * 1000] = 0.f;  // penalty
}

extern "C" void kernel_launch(void* const* d_in, const int* in_sizes, int n_in,
                              void* d_out, int out_size, void* d_ws, size_t ws_size,
                              hipStream_t stream) {
    const float* x    = (const float*)d_in[0];
    // d_in[1] = labels (unused)
    const float* W    = (const float*)d_in[2];
    const float* bias = (const float*)d_in[3];
    float* out = (float*)d_out;

    // ws layout:
    //   Xf  f16 fragment-ordered  33,554,432 B
    //   Bf  f16 fragment-ordered   5,242,880 B
    //   Lh  f16 [8192][1280]      20,971,520 B   (total 59,768,832 B)
    f16* Xf = (f16*)d_ws;
    f16* Bf = (f16*)((char*)d_ws + 33554432);
    f16* Lh = (f16*)((char*)d_ws + 38797312);

    prep_x <<<MT * 32, 256, 0, stream>>>(x, Xf);
    prep_b <<<1280, 256, 0, stream>>>(W, Bf);
    gemm_f16<<<MT * NT, 512, 0, stream>>>(Xf, Bf, Lh);
    tree_epi<<<BROWS / 4, 256, 0, stream>>>(Lh, bias, out);
}

// Round 6
// 93.300 us; speedup vs baseline: 1.1456x; 1.1456x over previous
//
#include <hip/hip_runtime.h>
#include <hip/hip_bf16.h>
#include <hip/hip_fp16.h>

typedef _Float16 f16;
typedef __attribute__((ext_vector_type(8))) _Float16 f16x8;
typedef __attribute__((ext_vector_type(4))) float f32x4;

#define DIM     2048
#define BROWS   8192
#define NCOLS   1221      // 111 nodes * 11
#define NPAD    1280      // 10 tiles of 128
#define NNODES  111
#define BM      128
#define BN      128
#define BK      64
#define NKT     (DIM / BK)    // 32 K-steps
#define MT      (BROWS / BM)  // 64
#define NT      (NPAD / BN)   // 10
// Fragment image per (tile, kt64): 1024 chunks x 16B = 16 KB = 8192 f16.
// chunk c = (kk*8 + g)*64 + l ; lane l (r=l&15,q=l>>4) holds
//   row = g*16 + r , k = kk*32 + q*8 .. +8   (within the 128x64 tile)

// ---------------------------------------------------------------------------
// prep_x: x f32 [8192][2048] -> Xf f16 fragment-ordered (64 mt x 32 kt images)
// ---------------------------------------------------------------------------
__global__ __launch_bounds__(256) void prep_x(const float* __restrict__ X,
                                              f16* __restrict__ Xf) {
    __shared__ float T[128 * 68];
    int blk = blockIdx.x;                      // mt*32 + kt
    int mt = blk >> 5, kt = blk & 31;
    int t = threadIdx.x;
    int row = t >> 1, half = t & 1;
    const float* src = X + (size_t)(mt * 128 + row) * DIM + kt * 64 + half * 32;
    float* dst = T + row * 68 + half * 32;
    #pragma unroll
    for (int i = 0; i < 8; ++i) ((f32x4*)dst)[i] = ((const f32x4*)src)[i];
    __syncthreads();
    int w = t >> 6, l = t & 63, r = l & 15, q = l >> 4;
    f16* out = Xf + (size_t)blk * 8192;
    #pragma unroll
    for (int p = 0; p < 4; ++p) {
        int gk = p * 4 + w;                    // = kk*8 + g
        int kk = gk >> 3, g = gk & 7;
        const float* s = T + (g * 16 + r) * 68 + kk * 32 + q * 8;
        f32x4 a = *(const f32x4*)s;
        f32x4 b = *(const f32x4*)(s + 4);
        f16x8 h;
        h[0] = (f16)a[0]; h[1] = (f16)a[1]; h[2] = (f16)a[2]; h[3] = (f16)a[3];
        h[4] = (f16)b[0]; h[5] = (f16)b[1]; h[6] = (f16)b[2]; h[7] = (f16)b[3];
        *(f16x8*)(out + (size_t)(p * 256 + t) * 8) = h;   // coalesced
    }
}

// ---------------------------------------------------------------------------
// prep_b: W f32 [111][2048][11] -> Bf f16 fragment-ordered (10 nt x 32 kt)
// ---------------------------------------------------------------------------
__global__ void prep_b(const float* __restrict__ W, f16* __restrict__ Bf) {
    int idx = blockIdx.x * 256 + threadIdx.x;  // 327,680
    int c = idx & 1023, img = idx >> 10;       // img = nt*32 + kt
    int nt = img >> 5, kt = img & 31;
    int kk = c >> 9, g = (c >> 6) & 7, l = c & 63, r = l & 15, q = l >> 4;
    int col = nt * 128 + g * 16 + r;
    int d0  = kt * 64 + kk * 32 + q * 8;
    f16x8 v;
    if (col < NCOLS) {
        int n = col / 11, k = col - n * 11;
        const float* src = W + ((size_t)n * DIM + d0) * 11 + k;
        #pragma unroll
        for (int e = 0; e < 8; ++e) v[e] = (f16)src[(size_t)e * 11];
    } else {
        #pragma unroll
        for (int e = 0; e < 8; ++e) v[e] = (f16)0.f;
    }
    *(f16x8*)(Bf + (size_t)idx * 8) = v;
}

// ---------------------------------------------------------------------------
// GEMM: 128x128 tile, BK=64, 8 waves (wave-tile 64x32), DOUBLE-buffered 16KB
// images (64 KB LDS), counted s_waitcnt vmcnt(4): tile t+1's 4 loads stay in
// flight across both barriers while tile t is computed. Round-4 phase
// thickness + round-5 pipelining; MFMA order identical to round 4.
// ---------------------------------------------------------------------------
__global__ __launch_bounds__(512) void gemm_f16(const f16* __restrict__ Xf,
                                                const f16* __restrict__ Bf,
                                                f16* __restrict__ Lh) {
    __shared__ __align__(16) f16 As[2][8192];  // 16 KB per buffer
    __shared__ __align__(16) f16 Bs[2][8192];

    int bid = blockIdx.x;                      // 640 = 8 XCDs * 80
    int swz = (bid & 7) * 80 + (bid >> 3);
    int mt = swz / 10, nt = swz - mt * 10;

    int t = threadIdx.x, w = t >> 6, l = t & 63, r = l & 15, q = l >> 4;
    int wm = w >> 2, wn = w & 3;               // 2 x 4 wave grid, wave tile 64x32

    const f16* abase = Xf + (size_t)(mt * 32) * 8192 + (size_t)t * 8;
    const f16* bbase = Bf + (size_t)(nt * 32) * 8192 + (size_t)t * 8;

    f32x4 acc[4][2];
    #pragma unroll
    for (int i = 0; i < 4; ++i)
        #pragma unroll
        for (int j = 0; j < 2; ++j) acc[i][j] = (f32x4)0.f;

    // 4 global_load_lds per thread per tile (A: 2x16B, B: 2x16B)
#define STAGE(KT, C)                                                             \
    {                                                                            \
        const f16* asrc = abase + (size_t)(KT) * 8192;                           \
        const f16* bsrc = bbase + (size_t)(KT) * 8192;                           \
        _Pragma("unroll")                                                        \
        for (int p = 0; p < 2; ++p) {                                            \
            __builtin_amdgcn_global_load_lds(                                    \
                (const __attribute__((address_space(1))) void*)(asrc + p * 4096),\
                (__attribute__((address_space(3))) void*)(&As[C][p * 4096 + w * 512]), 16, 0, 0); \
            __builtin_amdgcn_global_load_lds(                                    \
                (const __attribute__((address_space(1))) void*)(bsrc + p * 4096),\
                (__attribute__((address_space(3))) void*)(&Bs[C][p * 4096 + w * 512]), 16, 0, 0); \
        }                                                                        \
    }

#define COMPUTE(C)                                                               \
    {                                                                            \
        _Pragma("unroll")                                                        \
        for (int kk = 0; kk < 2; ++kk) {                                         \
            f16x8 af[4], bfr[2];                                                 \
            _Pragma("unroll")                                                    \
            for (int m = 0; m < 4; ++m)                                          \
                af[m] = *(const f16x8*)(&As[C][((kk * 8 + wm * 4 + m) * 64 + l) * 8]); \
            _Pragma("unroll")                                                    \
            for (int n = 0; n < 2; ++n)                                          \
                bfr[n] = *(const f16x8*)(&Bs[C][((kk * 8 + wn * 2 + n) * 64 + l) * 8]); \
            _Pragma("unroll")                                                    \
            for (int m = 0; m < 4; ++m)                                          \
                _Pragma("unroll")                                                \
                for (int n = 0; n < 2; ++n)                                      \
                    acc[m][n] = __builtin_amdgcn_mfma_f32_16x16x32_f16(af[m], bfr[n], acc[m][n], 0, 0, 0); \
        }                                                                        \
    }

#define STEP(KTCUR, CC, CN)                                                      \
    {                                                                            \
        STAGE(KTCUR + 1, CN)                                                     \
        asm volatile("s_waitcnt vmcnt(4)" ::: "memory");                         \
        __builtin_amdgcn_s_barrier();                                            \
        COMPUTE(CC)                                                              \
        asm volatile("s_waitcnt lgkmcnt(0)" ::: "memory");                       \
        __builtin_amdgcn_s_barrier();                                            \
    }

    // prologue: stage tile 0 into buffer 0 (4 loads in flight)
    STAGE(0, 0)
    // main loop: 30 pipelined steps (tiles 0..29), parity-unrolled
    for (int kt = 0; kt < 30; kt += 2) {
        STEP(kt,     0, 1)
        STEP(kt + 1, 1, 0)
    }
    // kt = 30: stage tile 31, compute tile 30 (buffer 0)
    STEP(30, 0, 1)
    // tail: tile 31 in buffer 1, nothing left to prefetch
    asm volatile("s_waitcnt vmcnt(0)" ::: "memory");
    __builtin_amdgcn_s_barrier();
    COMPUTE(1)

#undef STAGE
#undef COMPUTE
#undef STEP

    // C write (f16): col = lane&15, row = (lane>>4)*4 + j (verified r1-r5)
    #pragma unroll
    for (int m = 0; m < 4; ++m) {
        int row = mt * 128 + wm * 64 + m * 16 + q * 4;
        #pragma unroll
        for (int n = 0; n < 2; ++n) {
            int col = nt * 128 + wn * 32 + n * 16 + r;
            #pragma unroll
            for (int j = 0; j < 4; ++j)
                Lh[(size_t)(row + j) * NPAD + col] = (f16)acc[m][n][j];
        }
    }
}

// ---------- epilogue: softmax per node (k=11) + 3-level product tree ----------
__global__ void tree_epi(const f16* __restrict__ L, const float* __restrict__ bias,
                         float* __restrict__ out) {
    __shared__ float P[4][NNODES * 11];
    __shared__ f16 R[4][NPAD];
    int w = threadIdx.x >> 6, l = threadIdx.x & 63;
    int row = blockIdx.x * 4 + w;

    const f16x8* src = (const f16x8*)(L + (size_t)row * NPAD);
    f16x8* dst = (f16x8*)R[w];
    dst[l]      = src[l];
    dst[l + 64] = src[l + 64];
    if (l < 32) dst[l + 128] = src[l + 128];

    for (int n = l; n < NNODES; n += 64) {
        float v[11], mx = -1e30f;
        #pragma unroll
        for (int k = 0; k < 11; ++k) { v[k] = (float)R[w][n * 11 + k] + bias[n * 11 + k]; mx = fmaxf(mx, v[k]); }
        float s = 0.f;
        #pragma unroll
        for (int k = 0; k < 11; ++k) { v[k] = __expf(v[k] - mx); s += v[k]; }
        float inv = 1.f / s;
        #pragma unroll
        for (int k = 0; k < 11; ++k) P[w][n * 11 + k] = v[k] * inv;
    }
    __syncthreads();
    const float* Pw = P[w];
    for (int c = l; c < 1000; c += 64) {
        int i  = c / 100;
        int j  = (c % 100) / 10;
        int mm = c % 10;
        float p = Pw[1 + i] * Pw[(1 + i) * 11 + 1 + j] * Pw[(11 + 10 * i + j) * 11 + 1 + mm];
        out[(size_t)row * 1000 + c] = p;
    }
    if (row == 0 && threadIdx.x == 0) out[(size_t)BROWS * 1000] = 0.f;  // penalty
}

extern "C" void kernel_launch(void* const* d_in, const int* in_sizes, int n_in,
                              void* d_out, int out_size, void* d_ws, size_t ws_size,
                              hipStream_t stream) {
    const float* x    = (const float*)d_in[0];
    // d_in[1] = labels (unused)
    const float* W    = (const float*)d_in[2];
    const float* bias = (const float*)d_in[3];
    float* out = (float*)d_out;

    // ws layout:
    //   Xf  f16 fragment-ordered  33,554,432 B
    //   Bf  f16 fragment-ordered   5,242,880 B
    //   Lh  f16 [8192][1280]      20,971,520 B   (total 59,768,832 B)
    f16* Xf = (f16*)d_ws;
    f16* Bf = (f16*)((char*)d_ws + 33554432);
    f16* Lh = (f16*)((char*)d_ws + 38797312);

    prep_x <<<MT * 32, 256, 0, stream>>>(x, Xf);
    prep_b <<<1280, 256, 0, stream>>>(W, Bf);
    gemm_f16<<<MT * NT, 512, 0, stream>>>(Xf, Bf, Lh);
    tree_epi<<<BROWS / 4, 256, 0, stream>>>(Lh, bias, out);
}